// Round 2
// baseline (203.985 us; speedup 1.0000x reference)
//
#include <hip/hip_runtime.h>

typedef __bf16 bf16x8 __attribute__((ext_vector_type(8)));
typedef unsigned short u16;
typedef unsigned short u16x8 __attribute__((ext_vector_type(8)));
typedef float f32x4 __attribute__((ext_vector_type(4)));

__device__ __forceinline__ float bf2f(u16 x) {
    unsigned u = ((unsigned)x) << 16;
    return __builtin_bit_cast(float, u);
}
__device__ __forceinline__ u16 f2bf(float f) {
    unsigned u = __builtin_bit_cast(unsigned, f);
    u += 0x7FFFu + ((u >> 16) & 1u);
    return (u16)(u >> 16);
}

// f32 -> bf16 (RNE), 8 elements/thread, n must be divisible by 8.
__global__ void cvt_f32_bf16(const float* __restrict__ in, u16* __restrict__ out, int n8) {
    const int i = blockIdx.x * blockDim.x + threadIdx.x;
    if (i >= n8) return;
    const float4* p = reinterpret_cast<const float4*>(in) + (size_t)i * 2;
    const float4 a = p[0], b = p[1];
    u16x8 r;
    r[0] = f2bf(a.x); r[1] = f2bf(a.y); r[2] = f2bf(a.z); r[3] = f2bf(a.w);
    r[4] = f2bf(b.x); r[5] = f2bf(b.y); r[6] = f2bf(b.z); r[7] = f2bf(b.w);
    *(reinterpret_cast<u16x8*>(out) + i) = r;
}

// C[m,n] = sum_k A[m,k] * W[n,k] + bias[n]  (torch Linear), bf16 A/W, fp32 accum.
// Block: 512 thr = 8 waves (2m x 4n), block tile 128m x 256n, wave tile 64x64.
template <bool OUT_BF16>
__launch_bounds__(512)
__global__ void gemm_bt_bias(const u16* __restrict__ A, const u16* __restrict__ W,
                             const float* __restrict__ bias, void* __restrict__ Cv,
                             int M, int N, int K) {
    const int lane  = threadIdx.x & 63;
    const int w     = threadIdx.x >> 6;   // 0..7
    const int wm    = w >> 2;             // 0..1
    const int wn    = w & 3;              // 0..3
    const int row_l = lane & 15;
    const int grp   = lane >> 4;

    const int m0 = blockIdx.y * 128 + wm * 64;
    const int n0 = blockIdx.x * 256 + wn * 64;

    f32x4 acc[4][4];
#pragma unroll
    for (int mi = 0; mi < 4; ++mi)
#pragma unroll
        for (int ni = 0; ni < 4; ++ni)
            acc[mi][ni] = (f32x4){0.f, 0.f, 0.f, 0.f};

    const int kiters = K >> 5;
    for (int it = 0; it < kiters; ++it) {
        const int k0 = it * 32 + grp * 8;
        bf16x8 a[4], b[4];
#pragma unroll
        for (int mi = 0; mi < 4; ++mi)
            a[mi] = *reinterpret_cast<const bf16x8*>(A + (size_t)(m0 + mi * 16 + row_l) * K + k0);
#pragma unroll
        for (int ni = 0; ni < 4; ++ni)
            b[ni] = *reinterpret_cast<const bf16x8*>(W + (size_t)(n0 + ni * 16 + row_l) * K + k0);
#pragma unroll
        for (int mi = 0; mi < 4; ++mi)
#pragma unroll
            for (int ni = 0; ni < 4; ++ni)
                acc[mi][ni] = __builtin_amdgcn_mfma_f32_16x16x32_bf16(a[mi], b[ni], acc[mi][ni], 0, 0, 0);
    }

#pragma unroll
    for (int ni = 0; ni < 4; ++ni) {
        const int col = n0 + ni * 16 + row_l;
        const float bsf = bias[col];
#pragma unroll
        for (int mi = 0; mi < 4; ++mi) {
#pragma unroll
            for (int r = 0; r < 4; ++r) {
                const int rowm = m0 + mi * 16 + grp * 4 + r;
                const float v = acc[mi][ni][r] + bsf;
                if (OUT_BF16)
                    ((u16*)Cv)[(size_t)rowm * N + col] = f2bf(v);
                else
                    ((float*)Cv)[(size_t)rowm * N + col] = v;
            }
        }
    }
}

// Banded local attention. One wave per (b, h, 16-query tile).
// qkv: [B*L, 1536] bf16 (Q | K | V, each 512 = 8 heads x 64).
// att: [B*L, 512] bf16, head-concat layout.
__launch_bounds__(64)
__global__ void local_attn(const u16* __restrict__ qkv, u16* __restrict__ att, int L) {
    const int lane  = threadIdx.x & 63;
    const int row_l = lane & 15;
    const int grp   = lane >> 4;
    const int qt = blockIdx.x, h = blockIdx.y, b = blockIdx.z;
    const int q0 = qt * 16;
    const size_t base = (size_t)(b * L) * 1536;

    // Q fragments (A-operand): q-row = row_l, k = grp*8 + j (+32 for second half of dh)
    const u16* qrow = qkv + base + (size_t)(q0 + row_l) * 1536 + h * 64;
    const bf16x8 qf0 = *reinterpret_cast<const bf16x8*>(qrow + grp * 8);
    const bf16x8 qf1 = *reinterpret_cast<const bf16x8*>(qrow + 32 + grp * 8);

    float mrow[4] = {-1e30f, -1e30f, -1e30f, -1e30f};
    float lrow[4] = {0.f, 0.f, 0.f, 0.f};
    f32x4 acc[4];
#pragma unroll
    for (int ds = 0; ds < 4; ++ds) acc[ds] = (f32x4){0.f, 0.f, 0.f, 0.f};

    __shared__ u16 P[16][32];  // P tile for LDS round-trip (C-layout -> A-layout)

    for (int c = 0; c < 5; ++c) {
        const int kc = q0 - 64 + 32 * c;
        if (kc + 32 <= 0) continue;
        if (kc >= L) break;

        // --- scores: S[q, key] for 2 key subtiles of 16 ---
        f32x4 s[2];
#pragma unroll
        for (int f = 0; f < 2; ++f) {
            const int key  = kc + 16 * f + row_l;
            const int keyc = min(max(key, 0), L - 1);
            const u16* krow = qkv + base + (size_t)keyc * 1536 + 512 + h * 64;
            const bf16x8 kf0 = *reinterpret_cast<const bf16x8*>(krow + grp * 8);
            const bf16x8 kf1 = *reinterpret_cast<const bf16x8*>(krow + 32 + grp * 8);
            f32x4 z = (f32x4){0.f, 0.f, 0.f, 0.f};
            z = __builtin_amdgcn_mfma_f32_16x16x32_bf16(qf0, kf0, z, 0, 0, 0);
            z = __builtin_amdgcn_mfma_f32_16x16x32_bf16(qf1, kf1, z, 0, 0, 0);
            s[f] = z;
        }

        // --- mask + online softmax (rows owned by this lane: q0 + grp*4 + r) ---
        float sv[2][4];
        bool  ok[2][4];
#pragma unroll
        for (int f = 0; f < 2; ++f) {
            const int key = kc + 16 * f + row_l;
#pragma unroll
            for (int r = 0; r < 4; ++r) {
                const int q = q0 + grp * 4 + r;
                const bool good = (key >= 0) && (key < L) && (key >= q - 64) && (key <= q + 64);
                ok[f][r] = good;
                sv[f][r] = good ? s[f][r] * 0.125f : -1e30f;
            }
        }
        float rmax[4];
#pragma unroll
        for (int r = 0; r < 4; ++r) rmax[r] = fmaxf(sv[0][r], sv[1][r]);
#pragma unroll
        for (int off = 1; off < 16; off <<= 1)
#pragma unroll
            for (int r = 0; r < 4; ++r)
                rmax[r] = fmaxf(rmax[r], __shfl_xor(rmax[r], off, 64));

        float scl[4];
#pragma unroll
        for (int r = 0; r < 4; ++r) {
            const float mn = fmaxf(mrow[r], rmax[r]);
            scl[r] = __expf(mrow[r] - mn);
            mrow[r] = mn;
        }
        float p[2][4], rsum[4];
#pragma unroll
        for (int r = 0; r < 4; ++r) {
            p[0][r] = ok[0][r] ? __expf(sv[0][r] - mrow[r]) : 0.f;
            p[1][r] = ok[1][r] ? __expf(sv[1][r] - mrow[r]) : 0.f;
            rsum[r] = p[0][r] + p[1][r];
        }
#pragma unroll
        for (int off = 1; off < 16; off <<= 1)
#pragma unroll
            for (int r = 0; r < 4; ++r)
                rsum[r] += __shfl_xor(rsum[r], off, 64);
#pragma unroll
        for (int r = 0; r < 4; ++r) lrow[r] = lrow[r] * scl[r] + rsum[r];
#pragma unroll
        for (int ds = 0; ds < 4; ++ds)
#pragma unroll
            for (int r = 0; r < 4; ++r)
                acc[ds][r] *= scl[r];

        // --- P -> LDS (C-layout write), read back in A-layout ---
        __syncthreads();  // WAR vs previous chunk's read
#pragma unroll
        for (int f = 0; f < 2; ++f)
#pragma unroll
            for (int r = 0; r < 4; ++r)
                P[grp * 4 + r][16 * f + row_l] = f2bf(p[f][r]);
        __syncthreads();
        const bf16x8 pa = *reinterpret_cast<const bf16x8*>(&P[row_l][grp * 8]);

        // --- PV: V gathered strided (B-operand layout), masked keys have p=0 ---
        u16x8 vb[4];
#pragma unroll
        for (int bb = 0; bb < 8; ++bb) {
            const int keyc = min(max(kc + grp * 8 + bb, 0), L - 1);
            const u16* vrow = qkv + base + (size_t)keyc * 1536 + 1024 + h * 64 + row_l;
#pragma unroll
            for (int ds = 0; ds < 4; ++ds) vb[ds][bb] = vrow[ds * 16];
        }
#pragma unroll
        for (int ds = 0; ds < 4; ++ds)
            acc[ds] = __builtin_amdgcn_mfma_f32_16x16x32_bf16(
                pa, __builtin_bit_cast(bf16x8, vb[ds]), acc[ds], 0, 0, 0);
    }

    // --- epilogue: normalize + store (att[b*L+q][h*64+d]) ---
#pragma unroll
    for (int r = 0; r < 4; ++r) {
        const float inv = 1.f / lrow[r];
        const int q = q0 + grp * 4 + r;
#pragma unroll
        for (int ds = 0; ds < 4; ++ds)
            att[(size_t)(b * L + q) * 512 + h * 64 + ds * 16 + row_l] = f2bf(acc[ds][r] * inv);
    }
}

extern "C" void kernel_launch(void* const* d_in, const int* in_sizes, int n_in,
                              void* d_out, int out_size, void* d_ws, size_t ws_size,
                              hipStream_t stream) {
    const float* x     = (const float*)d_in[0];
    const float* w_in  = (const float*)d_in[1];
    const float* b_in  = (const float*)d_in[2];
    const float* w_out = (const float*)d_in[3];
    const float* b_out = (const float*)d_in[4];
    float* out = (float*)d_out;

    const int B = 8, L = 2048;
    const int M = B * L;  // 16384

    // workspace layout (u16 units)
    u16* qkv   = (u16*)d_ws;                      // [M, 1536]  bf16
    u16* att   = qkv   + (size_t)M * 1536;        // [M, 512]   bf16
    u16* x_bf  = att   + (size_t)M * 512;         // [M, 512]   bf16
    u16* wi_bf = x_bf  + (size_t)M * 512;         // [1536, 512] bf16
    u16* wo_bf = wi_bf + (size_t)1536 * 512;      // [512, 512] bf16

    // f32 -> bf16 conversions (once per call)
    {
        const int nx = M * 512 / 8;
        cvt_f32_bf16<<<(nx + 255) / 256, 256, 0, stream>>>(x, x_bf, nx);
        const int nwi = 1536 * 512 / 8;
        cvt_f32_bf16<<<(nwi + 255) / 256, 256, 0, stream>>>(w_in, wi_bf, nwi);
        const int nwo = 512 * 512 / 8;
        cvt_f32_bf16<<<(nwo + 255) / 256, 256, 0, stream>>>(w_out, wo_bf, nwo);
    }

    // QKV projection: grid x = n-tiles (fastest -> A-panel L2 reuse), y = m-tiles
    gemm_bt_bias<true><<<dim3(1536 / 256, M / 128), dim3(512), 0, stream>>>(
        x_bf, wi_bf, b_in, qkv, M, 1536, 512);

    // banded attention
    local_attn<<<dim3(L / 16, 8, B), dim3(64), 0, stream>>>(qkv, att, L);

    // output projection -> d_out (f32 + bias)
    gemm_bt_bias<false><<<dim3(512 / 256, M / 128), dim3(512), 0, stream>>>(
        att, wo_bf, b_out, out, M, 512, 512);
}

// Round 3
// 131.007 us; speedup vs baseline: 1.5571x; 1.5571x over previous
//
#include <hip/hip_runtime.h>

typedef __bf16 bf16x8 __attribute__((ext_vector_type(8)));
typedef unsigned short u16;
typedef unsigned short u16x8 __attribute__((ext_vector_type(8)));
typedef float f32x4 __attribute__((ext_vector_type(4)));

__device__ __forceinline__ float bf2f(u16 x) {
    unsigned u = ((unsigned)x) << 16;
    return __builtin_bit_cast(float, u);
}
__device__ __forceinline__ u16 f2bf(float f) {
    unsigned u = __builtin_bit_cast(unsigned, f);
    u += 0x7FFFu + ((u >> 16) & 1u);
    return (u16)(u >> 16);
}

__device__ __forceinline__ void gload_lds16(const u16* g, u16* l) {
    __builtin_amdgcn_global_load_lds(
        (const __attribute__((address_space(1))) void*)g,
        (__attribute__((address_space(3))) void*)l, 16, 0, 0);
}

// f32 -> bf16 (RNE), 8 elements/thread.
__global__ void cvt_f32_bf16(const float* __restrict__ in, u16* __restrict__ out, int n8) {
    const int i = blockIdx.x * blockDim.x + threadIdx.x;
    if (i >= n8) return;
    const float4* p = reinterpret_cast<const float4*>(in) + (size_t)i * 2;
    const float4 a = p[0], b = p[1];
    u16x8 r;
    r[0] = f2bf(a.x); r[1] = f2bf(a.y); r[2] = f2bf(a.z); r[3] = f2bf(a.w);
    r[4] = f2bf(b.x); r[5] = f2bf(b.y); r[6] = f2bf(b.z); r[7] = f2bf(b.w);
    *(reinterpret_cast<u16x8*>(out) + i) = r;
}

// C[m,n] = sum_k A[m,k] * W[n,k] + bias[n]  (torch Linear), bf16 A/W, fp32 accum.
// m97 structure: 256 thr = 4 waves (2x2), block tile 128x128, BK=32,
// single-buffered LDS staged via global_load_lds width=16, 2 barriers/K-step.
template <bool OUT_BF16>
__launch_bounds__(256)
__global__ void gemm_bt_bias(const u16* __restrict__ A, const u16* __restrict__ W,
                             const float* __restrict__ bias, void* __restrict__ Cv,
                             int M, int N, int K) {
    __shared__ u16 As[128 * 32];
    __shared__ u16 Bs[128 * 32];

    const int tid   = threadIdx.x;
    const int lane  = tid & 63;
    const int wid   = tid >> 6;           // 0..3
    const int wm    = wid >> 1;           // 0..1
    const int wn    = wid & 1;            // 0..1
    const int row_l = lane & 15;
    const int grp   = lane >> 4;

    const int m0 = blockIdx.y * 128;
    const int n0 = blockIdx.x * 128;

    // staging map: issue i covers rows [i*64, i*64+64); thread -> (row, col8)
    const int st_row = tid >> 2;          // 0..63
    const int st_col = (tid & 3) * 8;     // 0,8,16,24
    const u16* gA = A + (size_t)(m0 + st_row) * K + st_col;
    const u16* gB = W + (size_t)(n0 + st_row) * K + st_col;
    // wave-uniform LDS dests (HW adds lane*16B)
    u16* lA = As + wid * 512;             // issue i adds i*2048
    u16* lB = Bs + wid * 512;

    f32x4 acc[4][4];
#pragma unroll
    for (int mi = 0; mi < 4; ++mi)
#pragma unroll
        for (int ni = 0; ni < 4; ++ni)
            acc[mi][ni] = (f32x4){0.f, 0.f, 0.f, 0.f};

    for (int k0 = 0; k0 < K; k0 += 32) {
#pragma unroll
        for (int i = 0; i < 2; ++i) {
            gload_lds16(gA + (size_t)i * 64 * K + k0, lA + i * 2048);
            gload_lds16(gB + (size_t)i * 64 * K + k0, lB + i * 2048);
        }
        __syncthreads();

        bf16x8 a[4], b[4];
#pragma unroll
        for (int mi = 0; mi < 4; ++mi)
            a[mi] = *reinterpret_cast<const bf16x8*>(&As[(wm * 64 + mi * 16 + row_l) * 32 + grp * 8]);
#pragma unroll
        for (int ni = 0; ni < 4; ++ni)
            b[ni] = *reinterpret_cast<const bf16x8*>(&Bs[(wn * 64 + ni * 16 + row_l) * 32 + grp * 8]);
#pragma unroll
        for (int mi = 0; mi < 4; ++mi)
#pragma unroll
            for (int ni = 0; ni < 4; ++ni)
                acc[mi][ni] = __builtin_amdgcn_mfma_f32_16x16x32_bf16(a[mi], b[ni], acc[mi][ni], 0, 0, 0);
        __syncthreads();
    }

#pragma unroll
    for (int ni = 0; ni < 4; ++ni) {
        const int col = n0 + wn * 64 + ni * 16 + row_l;
        const float bsf = bias[col];
#pragma unroll
        for (int mi = 0; mi < 4; ++mi) {
#pragma unroll
            for (int r = 0; r < 4; ++r) {
                const int rowm = m0 + wm * 64 + mi * 16 + grp * 4 + r;
                const float v = acc[mi][ni][r] + bsf;
                if (OUT_BF16)
                    ((u16*)Cv)[(size_t)rowm * N + col] = f2bf(v);
                else
                    ((float*)Cv)[(size_t)rowm * N + col] = v;
            }
        }
    }
}

// Banded local attention. One wave per (b, h, 16-query tile).
// qkv: [B*L, 1536] bf16 (Q | K | V, each 512 = 8 heads x 64).
// att: [B*L, 512] bf16, head-concat layout.
__launch_bounds__(64)
__global__ void local_attn(const u16* __restrict__ qkv, u16* __restrict__ att, int L) {
    const int lane  = threadIdx.x & 63;
    const int row_l = lane & 15;
    const int grp   = lane >> 4;
    const int qt = blockIdx.x, h = blockIdx.y, b = blockIdx.z;
    const int q0 = qt * 16;
    const size_t base = (size_t)(b * L) * 1536;

    const u16* qrow = qkv + base + (size_t)(q0 + row_l) * 1536 + h * 64;
    const bf16x8 qf0 = *reinterpret_cast<const bf16x8*>(qrow + grp * 8);
    const bf16x8 qf1 = *reinterpret_cast<const bf16x8*>(qrow + 32 + grp * 8);

    float mrow[4] = {-1e30f, -1e30f, -1e30f, -1e30f};
    float lrow[4] = {0.f, 0.f, 0.f, 0.f};
    f32x4 acc[4];
#pragma unroll
    for (int ds = 0; ds < 4; ++ds) acc[ds] = (f32x4){0.f, 0.f, 0.f, 0.f};

    __shared__ u16 P[16][32];

    for (int c = 0; c < 5; ++c) {
        const int kc = q0 - 64 + 32 * c;
        if (kc + 32 <= 0) continue;
        if (kc >= L) break;

        f32x4 s[2];
#pragma unroll
        for (int f = 0; f < 2; ++f) {
            const int key  = kc + 16 * f + row_l;
            const int keyc = min(max(key, 0), L - 1);
            const u16* krow = qkv + base + (size_t)keyc * 1536 + 512 + h * 64;
            const bf16x8 kf0 = *reinterpret_cast<const bf16x8*>(krow + grp * 8);
            const bf16x8 kf1 = *reinterpret_cast<const bf16x8*>(krow + 32 + grp * 8);
            f32x4 z = (f32x4){0.f, 0.f, 0.f, 0.f};
            z = __builtin_amdgcn_mfma_f32_16x16x32_bf16(qf0, kf0, z, 0, 0, 0);
            z = __builtin_amdgcn_mfma_f32_16x16x32_bf16(qf1, kf1, z, 0, 0, 0);
            s[f] = z;
        }

        float sv[2][4];
        bool  ok[2][4];
#pragma unroll
        for (int f = 0; f < 2; ++f) {
            const int key = kc + 16 * f + row_l;
#pragma unroll
            for (int r = 0; r < 4; ++r) {
                const int q = q0 + grp * 4 + r;
                const bool good = (key >= 0) && (key < L) && (key >= q - 64) && (key <= q + 64);
                ok[f][r] = good;
                sv[f][r] = good ? s[f][r] * 0.125f : -1e30f;
            }
        }
        float rmax[4];
#pragma unroll
        for (int r = 0; r < 4; ++r) rmax[r] = fmaxf(sv[0][r], sv[1][r]);
#pragma unroll
        for (int off = 1; off < 16; off <<= 1)
#pragma unroll
            for (int r = 0; r < 4; ++r)
                rmax[r] = fmaxf(rmax[r], __shfl_xor(rmax[r], off, 64));

        float scl[4];
#pragma unroll
        for (int r = 0; r < 4; ++r) {
            const float mn = fmaxf(mrow[r], rmax[r]);
            scl[r] = __expf(mrow[r] - mn);
            mrow[r] = mn;
        }
        float p[2][4], rsum[4];
#pragma unroll
        for (int r = 0; r < 4; ++r) {
            p[0][r] = ok[0][r] ? __expf(sv[0][r] - mrow[r]) : 0.f;
            p[1][r] = ok[1][r] ? __expf(sv[1][r] - mrow[r]) : 0.f;
            rsum[r] = p[0][r] + p[1][r];
        }
#pragma unroll
        for (int off = 1; off < 16; off <<= 1)
#pragma unroll
            for (int r = 0; r < 4; ++r)
                rsum[r] += __shfl_xor(rsum[r], off, 64);
#pragma unroll
        for (int r = 0; r < 4; ++r) lrow[r] = lrow[r] * scl[r] + rsum[r];
#pragma unroll
        for (int ds = 0; ds < 4; ++ds)
#pragma unroll
            for (int r = 0; r < 4; ++r)
                acc[ds][r] *= scl[r];

        __syncthreads();
#pragma unroll
        for (int f = 0; f < 2; ++f)
#pragma unroll
            for (int r = 0; r < 4; ++r)
                P[grp * 4 + r][16 * f + row_l] = f2bf(p[f][r]);
        __syncthreads();
        const bf16x8 pa = *reinterpret_cast<const bf16x8*>(&P[row_l][grp * 8]);

        u16x8 vb[4];
#pragma unroll
        for (int bb = 0; bb < 8; ++bb) {
            const int keyc = min(max(kc + grp * 8 + bb, 0), L - 1);
            const u16* vrow = qkv + base + (size_t)keyc * 1536 + 1024 + h * 64 + row_l;
#pragma unroll
            for (int ds = 0; ds < 4; ++ds) vb[ds][bb] = vrow[ds * 16];
        }
#pragma unroll
        for (int ds = 0; ds < 4; ++ds)
            acc[ds] = __builtin_amdgcn_mfma_f32_16x16x32_bf16(
                pa, __builtin_bit_cast(bf16x8, vb[ds]), acc[ds], 0, 0, 0);
    }

#pragma unroll
    for (int r = 0; r < 4; ++r) {
        const float inv = 1.f / lrow[r];
        const int q = q0 + grp * 4 + r;
#pragma unroll
        for (int ds = 0; ds < 4; ++ds)
            att[(size_t)(b * L + q) * 512 + h * 64 + ds * 16 + row_l] = f2bf(acc[ds][r] * inv);
    }
}

extern "C" void kernel_launch(void* const* d_in, const int* in_sizes, int n_in,
                              void* d_out, int out_size, void* d_ws, size_t ws_size,
                              hipStream_t stream) {
    const float* x     = (const float*)d_in[0];
    const float* w_in  = (const float*)d_in[1];
    const float* b_in  = (const float*)d_in[2];
    const float* w_out = (const float*)d_in[3];
    const float* b_out = (const float*)d_in[4];
    float* out = (float*)d_out;

    const int B = 8, L = 2048;
    const int M = B * L;  // 16384

    u16* qkv   = (u16*)d_ws;                      // [M, 1536]  bf16
    u16* att   = qkv   + (size_t)M * 1536;        // [M, 512]   bf16
    u16* x_bf  = att   + (size_t)M * 512;         // [M, 512]   bf16
    u16* wi_bf = x_bf  + (size_t)M * 512;         // [1536, 512] bf16
    u16* wo_bf = wi_bf + (size_t)1536 * 512;      // [512, 512] bf16

    {
        const int nx = M * 512 / 8;
        cvt_f32_bf16<<<(nx + 255) / 256, 256, 0, stream>>>(x, x_bf, nx);
        const int nwi = 1536 * 512 / 8;
        cvt_f32_bf16<<<(nwi + 255) / 256, 256, 0, stream>>>(w_in, wi_bf, nwi);
        const int nwo = 512 * 512 / 8;
        cvt_f32_bf16<<<(nwo + 255) / 256, 256, 0, stream>>>(w_out, wo_bf, nwo);
    }

    gemm_bt_bias<true><<<dim3(1536 / 128, M / 128), dim3(256), 0, stream>>>(
        x_bf, wi_bf, b_in, qkv, M, 1536, 512);

    local_attn<<<dim3(L / 16, 8, B), dim3(64), 0, stream>>>(qkv, att, L);

    gemm_bt_bias<false><<<dim3(512 / 128, M / 128), dim3(256), 0, stream>>>(
        att, wo_bf, b_out, out, M, 512, 512);
}

// Round 4
// 103.953 us; speedup vs baseline: 1.9623x; 1.2603x over previous
//
#include <hip/hip_runtime.h>

typedef __bf16 bf16x8 __attribute__((ext_vector_type(8)));
typedef unsigned short u16;
typedef unsigned short u16x8 __attribute__((ext_vector_type(8)));
typedef float f32x4 __attribute__((ext_vector_type(4)));

#define L_SEQ 2048
#define NQT   (L_SEQ / 128)

__device__ __forceinline__ float bf2f(u16 x) {
    unsigned u = ((unsigned)x) << 16;
    return __builtin_bit_cast(float, u);
}
__device__ __forceinline__ u16 f2bf(float f) {
    unsigned u = __builtin_bit_cast(unsigned, f);
    u += 0x7FFFu + ((u >> 16) & 1u);
    return (u16)(u >> 16);
}

__device__ __forceinline__ void gload_lds16(const u16* g, u16* l) {
    __builtin_amdgcn_global_load_lds(
        (const __attribute__((address_space(1))) void*)g,
        (__attribute__((address_space(3))) void*)l, 16, 0, 0);
}

// f32 -> bf16 (RNE), 8 elements/thread.
__global__ void cvt_f32_bf16(const float* __restrict__ in, u16* __restrict__ out, int n8) {
    const int i = blockIdx.x * blockDim.x + threadIdx.x;
    if (i >= n8) return;
    const float4* p = reinterpret_cast<const float4*>(in) + (size_t)i * 2;
    const float4 a = p[0], b = p[1];
    u16x8 r;
    r[0] = f2bf(a.x); r[1] = f2bf(a.y); r[2] = f2bf(a.z); r[3] = f2bf(a.w);
    r[4] = f2bf(b.x); r[5] = f2bf(b.y); r[6] = f2bf(b.z); r[7] = f2bf(b.w);
    *(reinterpret_cast<u16x8*>(out) + i) = r;
}

// C[m,n] = sum_k A[m,k] * W[n,k] + bias[n]  (torch Linear), bf16 A/W, fp32 accum.
// m97 structure: 256 thr = 4 waves (2x2), block tile 128x128, BK=32,
// single-buffered LDS staged via global_load_lds width=16, 2 barriers/K-step.
template <bool OUT_BF16>
__launch_bounds__(256)
__global__ void gemm_bt_bias(const u16* __restrict__ A, const u16* __restrict__ W,
                             const float* __restrict__ bias, void* __restrict__ Cv,
                             int M, int N, int K) {
    __shared__ u16 As[128 * 32];
    __shared__ u16 Bs[128 * 32];

    const int tid   = threadIdx.x;
    const int lane  = tid & 63;
    const int wid   = tid >> 6;
    const int wm    = wid >> 1;
    const int wn    = wid & 1;
    const int row_l = lane & 15;
    const int grp   = lane >> 4;

    const int m0 = blockIdx.y * 128;
    const int n0 = blockIdx.x * 128;

    const int st_row = tid >> 2;
    const int st_col = (tid & 3) * 8;
    const u16* gA = A + (size_t)(m0 + st_row) * K + st_col;
    const u16* gB = W + (size_t)(n0 + st_row) * K + st_col;
    u16* lA = As + wid * 512;
    u16* lB = Bs + wid * 512;

    f32x4 acc[4][4];
#pragma unroll
    for (int mi = 0; mi < 4; ++mi)
#pragma unroll
        for (int ni = 0; ni < 4; ++ni)
            acc[mi][ni] = (f32x4){0.f, 0.f, 0.f, 0.f};

    for (int k0 = 0; k0 < K; k0 += 32) {
#pragma unroll
        for (int i = 0; i < 2; ++i) {
            gload_lds16(gA + (size_t)i * 64 * K + k0, lA + i * 2048);
            gload_lds16(gB + (size_t)i * 64 * K + k0, lB + i * 2048);
        }
        __syncthreads();

        bf16x8 a[4], b[4];
#pragma unroll
        for (int mi = 0; mi < 4; ++mi)
            a[mi] = *reinterpret_cast<const bf16x8*>(&As[(wm * 64 + mi * 16 + row_l) * 32 + grp * 8]);
#pragma unroll
        for (int ni = 0; ni < 4; ++ni)
            b[ni] = *reinterpret_cast<const bf16x8*>(&Bs[(wn * 64 + ni * 16 + row_l) * 32 + grp * 8]);
#pragma unroll
        for (int mi = 0; mi < 4; ++mi)
#pragma unroll
            for (int ni = 0; ni < 4; ++ni)
                acc[mi][ni] = __builtin_amdgcn_mfma_f32_16x16x32_bf16(a[mi], b[ni], acc[mi][ni], 0, 0, 0);
        __syncthreads();
    }

#pragma unroll
    for (int ni = 0; ni < 4; ++ni) {
        const int col = n0 + wn * 64 + ni * 16 + row_l;
        const float bsf = bias[col];
#pragma unroll
        for (int mi = 0; mi < 4; ++mi) {
#pragma unroll
            for (int r = 0; r < 4; ++r) {
                const int rowm = m0 + wm * 64 + mi * 16 + grp * 4 + r;
                const float v = acc[mi][ni][r] + bsf;
                if (OUT_BF16)
                    ((u16*)Cv)[(size_t)rowm * N + col] = f2bf(v);
                else
                    ((float*)Cv)[(size_t)rowm * N + col] = v;
            }
        }
    }
}

// Banded local attention, block-shared K/V.
// Block = (qt, h, b): 512 thr / 8 waves, 128 queries; keys [q0b-64, q0b+192).
// qkv: [B*L, 1536] bf16 (Q|K|V); att: [B*L, 512] bf16 head-concat.
__launch_bounds__(512, 4)
__global__ void local_attn(const u16* __restrict__ qkv, u16* __restrict__ att) {
    // K tile: rows 0..255 (key - kstart), 64 d; swizzled: slot = col8 ^ (row&7)
    __shared__ __align__(16) u16 Ks[256 * 64];
    // V^T tile: [d=64][key=256]; swizzled: slot = (key>>3) ^ (d&7)
    __shared__ __align__(16) u16 Vt[64 * 256];
    // per-wave P tile [16 q][32 key]; slot = (k>>3) ^ ((q>>1)&3)
    __shared__ __align__(16) u16 Pl[8][512];

    const int tid   = threadIdx.x;
    const int lane  = tid & 63;
    const int wv    = tid >> 6;
    const int row_l = lane & 15;
    const int grp   = lane >> 4;
    const int qt = blockIdx.x, h = blockIdx.y, b = blockIdx.z;
    const int q0b = qt * 128;
    const int kstart = q0b - 64;
    const size_t base = (size_t)b * L_SEQ * 1536;
    const bool edge = (qt == 0) || (qt == NQT - 1);

    // ---- stage K via global_load_lds, source pre-swizzled ----
    {
        const int r0 = tid >> 3;
        const int c  = tid & 7;
#pragma unroll
        for (int i = 0; i < 4; ++i) {
            const int row  = i * 64 + r0;
            const int keyg = min(max(kstart + row, 0), L_SEQ - 1);
            const int cg   = c ^ (row & 7);
            gload_lds16(qkv + base + (size_t)keyg * 1536 + 512 + h * 64 + cg * 8,
                        &Ks[i * 4096 + wv * 512]);
        }
    }
    // ---- stage V transposed (reg-staged, swizzled scatter) ----
    {
#pragma unroll
        for (int i = 0; i < 4; ++i) {
            const int idx  = i * 512 + tid;
            const int row  = idx >> 3;       // local key
            const int c8   = idx & 7;        // d block of 8
            const int keyg = min(max(kstart + row, 0), L_SEQ - 1);
            const u16x8 vu = *reinterpret_cast<const u16x8*>(
                qkv + base + (size_t)keyg * 1536 + 1024 + h * 64 + c8 * 8);
#pragma unroll
            for (int e = 0; e < 8; ++e) {
                const int d = c8 * 8 + e;
                Vt[d * 256 + (((row >> 3) ^ (d & 7)) * 8) + (row & 7)] = vu[e];
            }
        }
    }

    // ---- Q fragments (B-operand for swapped QK^T): q = row_l, d = grp*8+j ----
    const int qrow_g = q0b + wv * 16 + row_l;
    const u16* qp = qkv + base + (size_t)qrow_g * 1536 + h * 64;
    const bf16x8 qf0 = *reinterpret_cast<const bf16x8*>(qp + grp * 8);
    const bf16x8 qf1 = *reinterpret_cast<const bf16x8*>(qp + 32 + grp * 8);

    __syncthreads();

    float m_r = -1e30f, l_r = 0.f;   // per-lane state for q-row = row_l
    f32x4 acc[4];
#pragma unroll
    for (int ds = 0; ds < 4; ++ds) acc[ds] = (f32x4){0.f, 0.f, 0.f, 0.f};
    u16* Pw = Pl[wv];

    auto do_chunk = [&](int c, bool bandLo, bool bandHi, bool half, bool rng) {
        const int kcL = wv * 16 + 32 * c;     // local key base of chunk
        const int kcG = kstart + kcL;
        const int nf = half ? 1 : 2;

        // swapped scores: mfma(K, Q) -> lane holds q=row_l, keys 16f+grp*4+r
        f32x4 s[2];
#pragma unroll
        for (int f = 0; f < 2; ++f) {
            if (f >= nf) break;
            const int rr = kcL + 16 * f + row_l;
            const bf16x8 ka = *reinterpret_cast<const bf16x8*>(
                &Ks[rr * 64 + ((grp ^ (rr & 7)) * 8)]);
            const bf16x8 kb = *reinterpret_cast<const bf16x8*>(
                &Ks[rr * 64 + (((grp + 4) ^ (rr & 7)) * 8)]);
            f32x4 z = (f32x4){0.f, 0.f, 0.f, 0.f};
            z = __builtin_amdgcn_mfma_f32_16x16x32_bf16(ka, qf0, z, 0, 0, 0);
            z = __builtin_amdgcn_mfma_f32_16x16x32_bf16(kb, qf1, z, 0, 0, 0);
            s[f] = z;
        }

        float p[2][4];
        float cmax = -1e30f;
#pragma unroll
        for (int f = 0; f < 2; ++f) {
            if (f >= nf) break;
#pragma unroll
            for (int r = 0; r < 4; ++r) {
                const int k = 16 * f + grp * 4 + r;
                bool ok = true;
                if (bandLo) ok = ok && (k >= row_l);
                if (bandHi) ok = ok && (k <= row_l);
                if (rng) { const int kg = kcG + k; ok = ok && (kg >= 0) && (kg < L_SEQ); }
                const float sv = ok ? s[f][r] * 0.125f : -1e30f;
                p[f][r] = sv;
                cmax = fmaxf(cmax, sv);
            }
        }
        cmax = fmaxf(cmax, __shfl_xor(cmax, 16, 64));
        cmax = fmaxf(cmax, __shfl_xor(cmax, 32, 64));
        const float mn  = fmaxf(m_r, cmax);
        const float scl = __expf(m_r - mn);
        m_r = mn;
        float lsum = 0.f;
#pragma unroll
        for (int f = 0; f < 2; ++f) {
            if (f >= nf) break;
#pragma unroll
            for (int r = 0; r < 4; ++r) {
                const float pv = (p[f][r] <= -1e29f) ? 0.f : __expf(p[f][r] - mn);
                p[f][r] = pv;
                lsum += pv;
            }
        }
        lsum += __shfl_xor(lsum, 16, 64);
        lsum += __shfl_xor(lsum, 32, 64);
        l_r = l_r * scl + lsum;

        // rescale acc (acc q = grp*4+r; scl held by lane grp*4+r)
        float scl4[4];
#pragma unroll
        for (int r = 0; r < 4; ++r) scl4[r] = __shfl(scl, grp * 4 + r, 64);
#pragma unroll
        for (int ds = 0; ds < 4; ++ds)
#pragma unroll
            for (int r = 0; r < 4; ++r) acc[ds][r] *= scl4[r];

        // P -> LDS (swizzled), then read back as A-fragment
#pragma unroll
        for (int f = 0; f < 2; ++f)
#pragma unroll
            for (int r = 0; r < 4; ++r) {
                const int k = 16 * f + grp * 4 + r;
                const int slot = (k >> 3) ^ ((row_l >> 1) & 3);
                const float pv = (f < nf) ? p[f][r] : 0.f;
                Pw[row_l * 32 + slot * 8 + (k & 7)] = f2bf(pv);
            }
        const bf16x8 pa = *reinterpret_cast<const bf16x8*>(
            &Pw[row_l * 32 + ((grp ^ ((row_l >> 1) & 3)) * 8)]);

        // PV: B = V^T; acc q = grp*4+r, d = ds*16+row_l
        int k0 = kcL + grp * 8;
        if (half) k0 = min(k0, 248);   // clamp; P rows >=16 are zero
#pragma unroll
        for (int ds = 0; ds < 4; ++ds) {
            const int d = ds * 16 + row_l;
            const bf16x8 vf = *reinterpret_cast<const bf16x8*>(
                &Vt[d * 256 + (((k0 >> 3) ^ (d & 7)) * 8)]);
            acc[ds] = __builtin_amdgcn_mfma_f32_16x16x32_bf16(pa, vf, acc[ds], 0, 0, 0);
        }
    };

    if (!edge) {
        do_chunk(0, true,  false, false, false);
        do_chunk(1, false, false, false, false);
        do_chunk(2, false, false, false, false);
        do_chunk(3, false, false, false, false);
        do_chunk(4, false, true,  true,  false);
    } else {
        const int kw = kstart + wv * 16;
        if (kw       > -32 && kw       < L_SEQ) do_chunk(0, true,  false, false, true);
        if (kw + 32  > -32 && kw + 32  < L_SEQ) do_chunk(1, false, false, false, true);
        if (kw + 64  > -32 && kw + 64  < L_SEQ) do_chunk(2, false, false, false, true);
        if (kw + 96  > -32 && kw + 96  < L_SEQ) do_chunk(3, false, false, false, true);
        if (kw + 128 > -32 && kw + 128 < L_SEQ) do_chunk(4, false, true,  true,  true);
    }

    // ---- epilogue: normalize + store ----
    const float inv = 1.f / l_r;
    float inv4[4];
#pragma unroll
    for (int r = 0; r < 4; ++r) inv4[r] = __shfl(inv, grp * 4 + r, 64);
    const int qg = q0b + wv * 16 + grp * 4;
#pragma unroll
    for (int r = 0; r < 4; ++r)
#pragma unroll
        for (int ds = 0; ds < 4; ++ds)
            att[(size_t)(b * L_SEQ + qg + r) * 512 + h * 64 + ds * 16 + row_l] =
                f2bf(acc[ds][r] * inv4[r]);
}

extern "C" void kernel_launch(void* const* d_in, const int* in_sizes, int n_in,
                              void* d_out, int out_size, void* d_ws, size_t ws_size,
                              hipStream_t stream) {
    const float* x     = (const float*)d_in[0];
    const float* w_in  = (const float*)d_in[1];
    const float* b_in  = (const float*)d_in[2];
    const float* w_out = (const float*)d_in[3];
    const float* b_out = (const float*)d_in[4];
    float* out = (float*)d_out;

    const int B = 8, L = L_SEQ;
    const int M = B * L;  // 16384

    u16* qkv   = (u16*)d_ws;                      // [M, 1536]  bf16
    u16* att   = qkv   + (size_t)M * 1536;        // [M, 512]   bf16
    u16* x_bf  = att   + (size_t)M * 512;         // [M, 512]   bf16
    u16* wi_bf = x_bf  + (size_t)M * 512;         // [1536, 512] bf16
    u16* wo_bf = wi_bf + (size_t)1536 * 512;      // [512, 512] bf16

    {
        const int nx = M * 512 / 8;
        cvt_f32_bf16<<<(nx + 255) / 256, 256, 0, stream>>>(x, x_bf, nx);
        const int nwi = 1536 * 512 / 8;
        cvt_f32_bf16<<<(nwi + 255) / 256, 256, 0, stream>>>(w_in, wi_bf, nwi);
        const int nwo = 512 * 512 / 8;
        cvt_f32_bf16<<<(nwo + 255) / 256, 256, 0, stream>>>(w_out, wo_bf, nwo);
    }

    gemm_bt_bias<true><<<dim3(1536 / 128, M / 128), dim3(256), 0, stream>>>(
        x_bf, wi_bf, b_in, qkv, M, 1536, 512);

    local_attn<<<dim3(NQT, 8, B), dim3(512), 0, stream>>>(qkv, att);

    gemm_bt_bias<false><<<dim3(512 / 128, M / 128), dim3(256), 0, stream>>>(
        att, wo_bf, b_out, out, M, 512, 512);
}

// Round 5
// 95.512 us; speedup vs baseline: 2.1357x; 1.0884x over previous
//
#include <hip/hip_runtime.h>

typedef __bf16 bf16x8 __attribute__((ext_vector_type(8)));
typedef unsigned short u16;
typedef unsigned short u16x8 __attribute__((ext_vector_type(8)));
typedef float f32x4 __attribute__((ext_vector_type(4)));

#define L_SEQ 2048
#define NQT   (L_SEQ / 128)

__device__ __forceinline__ float bf2f(u16 x) {
    unsigned u = ((unsigned)x) << 16;
    return __builtin_bit_cast(float, u);
}
__device__ __forceinline__ u16 f2bf(float f) {
    unsigned u = __builtin_bit_cast(unsigned, f);
    u += 0x7FFFu + ((u >> 16) & 1u);
    return (u16)(u >> 16);
}

__device__ __forceinline__ void gload_lds16(const u16* g, u16* l) {
    __builtin_amdgcn_global_load_lds(
        (const __attribute__((address_space(1))) void*)g,
        (__attribute__((address_space(3))) void*)l, 16, 0, 0);
}

// f32 -> bf16 (RNE), 8 elements/thread.
__global__ void cvt_f32_bf16(const float* __restrict__ in, u16* __restrict__ out, int n8) {
    const int i = blockIdx.x * blockDim.x + threadIdx.x;
    if (i >= n8) return;
    const float4* p = reinterpret_cast<const float4*>(in) + (size_t)i * 2;
    const float4 a = p[0], b = p[1];
    u16x8 r;
    r[0] = f2bf(a.x); r[1] = f2bf(a.y); r[2] = f2bf(a.z); r[3] = f2bf(a.w);
    r[4] = f2bf(b.x); r[5] = f2bf(b.y); r[6] = f2bf(b.z); r[7] = f2bf(b.w);
    *(reinterpret_cast<u16x8*>(out) + i) = r;
}

// C[m,n] = sum_k A[m,k] * W[n,k] + bias[n]  (torch Linear), bf16 A/W, fp32 accum.
// 256 thr = 4 waves (2x2), block tile 128x128, BK=64, double-buffered LDS,
// T2 XOR-swizzle (slot ^ row&7; rows are 128B), T3-minimum 2-phase prefetch,
// T1 bijective XCD swizzle (requires gridX*gridY % 8 == 0).
template <bool OUT_BF16>
__launch_bounds__(256)
__global__ void gemm_bt_bias(const u16* __restrict__ A, const u16* __restrict__ W,
                             const float* __restrict__ bias, void* __restrict__ Cv,
                             int M, int N, int K) {
    __shared__ u16 As[2][128 * 64];
    __shared__ u16 Bs[2][128 * 64];

    const int tid   = threadIdx.x;
    const int lane  = tid & 63;
    const int wid   = tid >> 6;
    const int wm    = wid >> 1;
    const int wn    = wid & 1;
    const int row_l = lane & 15;
    const int grp   = lane >> 4;

    // XCD-aware bijective tile remap: XCD c gets contiguous tile chunk.
    const int nwg  = gridDim.x * gridDim.y;
    const int hw   = blockIdx.y * gridDim.x + blockIdx.x;
    const int tile = (hw & 7) * (nwg >> 3) + (hw >> 3);
    const int m0 = (tile / gridDim.x) * 128;
    const int n0 = (tile % gridDim.x) * 128;

    // staging: thread -> (row, swizzled col); issue i adds 32 rows.
    // LDS linear dest element = i*2048 + tid*8 -> row = i*32 + (tid>>3), slot = tid&7.
    // source column pre-swizzled so LDS[row][slot] holds gcol = slot ^ (row&7).
    const int srow = tid >> 3;                       // 0..31
    const int scol = ((tid & 7) ^ (srow & 7)) * 8;
    const u16* gA = A + (size_t)(m0 + srow) * K + scol;
    const u16* gB = W + (size_t)(n0 + srow) * K + scol;

    f32x4 acc[4][4];
#pragma unroll
    for (int mi = 0; mi < 4; ++mi)
#pragma unroll
        for (int ni = 0; ni < 4; ++ni)
            acc[mi][ni] = (f32x4){0.f, 0.f, 0.f, 0.f};

    auto stage = [&](int buf, int kt) {
#pragma unroll
        for (int i = 0; i < 4; ++i) {
            gload_lds16(gA + (size_t)(i * 32) * K + kt * 64, &As[buf][i * 2048 + wid * 512]);
            gload_lds16(gB + (size_t)(i * 32) * K + kt * 64, &Bs[buf][i * 2048 + wid * 512]);
        }
    };

    auto compute = [&](int buf) {
#pragma unroll
        for (int kk = 0; kk < 2; ++kk) {
            bf16x8 a[4], b[4];
#pragma unroll
            for (int mi = 0; mi < 4; ++mi) {
                const int row = wm * 64 + mi * 16 + row_l;
                a[mi] = *reinterpret_cast<const bf16x8*>(
                    &As[buf][row * 64 + (((kk * 4 + grp) ^ (row & 7)) * 8)]);
            }
#pragma unroll
            for (int ni = 0; ni < 4; ++ni) {
                const int row = wn * 64 + ni * 16 + row_l;
                b[ni] = *reinterpret_cast<const bf16x8*>(
                    &Bs[buf][row * 64 + (((kk * 4 + grp) ^ (row & 7)) * 8)]);
            }
#pragma unroll
            for (int mi = 0; mi < 4; ++mi)
#pragma unroll
                for (int ni = 0; ni < 4; ++ni)
                    acc[mi][ni] = __builtin_amdgcn_mfma_f32_16x16x32_bf16(a[mi], b[ni], acc[mi][ni], 0, 0, 0);
        }
    };

    const int NT = K >> 6;
    stage(0, 0);
    __syncthreads();                 // vmcnt(0) drain + barrier: tile 0 ready
    for (int t = 0; t < NT - 1; ++t) {
        const int cur = t & 1;
        stage(cur ^ 1, t + 1);       // issue next-tile loads BEFORE compute
        compute(cur);                // ds_read + MFMA on current tile
        __syncthreads();             // drains vmcnt -> next tile ready; also WAR fence
    }
    compute((NT - 1) & 1);

#pragma unroll
    for (int ni = 0; ni < 4; ++ni) {
        const int col = n0 + wn * 64 + ni * 16 + row_l;
        const float bsf = bias[col];
#pragma unroll
        for (int mi = 0; mi < 4; ++mi) {
#pragma unroll
            for (int r = 0; r < 4; ++r) {
                const int rowm = m0 + wm * 64 + mi * 16 + grp * 4 + r;
                const float v = acc[mi][ni][r] + bsf;
                if (OUT_BF16)
                    ((u16*)Cv)[(size_t)rowm * N + col] = f2bf(v);
                else
                    ((float*)Cv)[(size_t)rowm * N + col] = v;
            }
        }
    }
}

// Banded local attention, block-shared K/V.  (unchanged from round 4)
__launch_bounds__(512, 4)
__global__ void local_attn(const u16* __restrict__ qkv, u16* __restrict__ att) {
    __shared__ __align__(16) u16 Ks[256 * 64];
    __shared__ __align__(16) u16 Vt[64 * 256];
    __shared__ __align__(16) u16 Pl[8][512];

    const int tid   = threadIdx.x;
    const int lane  = tid & 63;
    const int wv    = tid >> 6;
    const int row_l = lane & 15;
    const int grp   = lane >> 4;
    const int qt = blockIdx.x, h = blockIdx.y, b = blockIdx.z;
    const int q0b = qt * 128;
    const int kstart = q0b - 64;
    const size_t base = (size_t)b * L_SEQ * 1536;
    const bool edge = (qt == 0) || (qt == NQT - 1);

    {
        const int r0 = tid >> 3;
        const int c  = tid & 7;
#pragma unroll
        for (int i = 0; i < 4; ++i) {
            const int row  = i * 64 + r0;
            const int keyg = min(max(kstart + row, 0), L_SEQ - 1);
            const int cg   = c ^ (row & 7);
            gload_lds16(qkv + base + (size_t)keyg * 1536 + 512 + h * 64 + cg * 8,
                        &Ks[i * 4096 + wv * 512]);
        }
    }
    {
#pragma unroll
        for (int i = 0; i < 4; ++i) {
            const int idx  = i * 512 + tid;
            const int row  = idx >> 3;
            const int c8   = idx & 7;
            const int keyg = min(max(kstart + row, 0), L_SEQ - 1);
            const u16x8 vu = *reinterpret_cast<const u16x8*>(
                qkv + base + (size_t)keyg * 1536 + 1024 + h * 64 + c8 * 8);
#pragma unroll
            for (int e = 0; e < 8; ++e) {
                const int d = c8 * 8 + e;
                Vt[d * 256 + (((row >> 3) ^ (d & 7)) * 8) + (row & 7)] = vu[e];
            }
        }
    }

    const int qrow_g = q0b + wv * 16 + row_l;
    const u16* qp = qkv + base + (size_t)qrow_g * 1536 + h * 64;
    const bf16x8 qf0 = *reinterpret_cast<const bf16x8*>(qp + grp * 8);
    const bf16x8 qf1 = *reinterpret_cast<const bf16x8*>(qp + 32 + grp * 8);

    __syncthreads();

    float m_r = -1e30f, l_r = 0.f;
    f32x4 acc[4];
#pragma unroll
    for (int ds = 0; ds < 4; ++ds) acc[ds] = (f32x4){0.f, 0.f, 0.f, 0.f};
    u16* Pw = Pl[wv];

    auto do_chunk = [&](int c, bool bandLo, bool bandHi, bool half, bool rng) {
        const int kcL = wv * 16 + 32 * c;
        const int kcG = kstart + kcL;
        const int nf = half ? 1 : 2;

        f32x4 s[2];
#pragma unroll
        for (int f = 0; f < 2; ++f) {
            if (f >= nf) break;
            const int rr = kcL + 16 * f + row_l;
            const bf16x8 ka = *reinterpret_cast<const bf16x8*>(
                &Ks[rr * 64 + ((grp ^ (rr & 7)) * 8)]);
            const bf16x8 kb = *reinterpret_cast<const bf16x8*>(
                &Ks[rr * 64 + (((grp + 4) ^ (rr & 7)) * 8)]);
            f32x4 z = (f32x4){0.f, 0.f, 0.f, 0.f};
            z = __builtin_amdgcn_mfma_f32_16x16x32_bf16(ka, qf0, z, 0, 0, 0);
            z = __builtin_amdgcn_mfma_f32_16x16x32_bf16(kb, qf1, z, 0, 0, 0);
            s[f] = z;
        }

        float p[2][4];
        float cmax = -1e30f;
#pragma unroll
        for (int f = 0; f < 2; ++f) {
            if (f >= nf) break;
#pragma unroll
            for (int r = 0; r < 4; ++r) {
                const int k = 16 * f + grp * 4 + r;
                bool ok = true;
                if (bandLo) ok = ok && (k >= row_l);
                if (bandHi) ok = ok && (k <= row_l);
                if (rng) { const int kg = kcG + k; ok = ok && (kg >= 0) && (kg < L_SEQ); }
                const float sv = ok ? s[f][r] * 0.125f : -1e30f;
                p[f][r] = sv;
                cmax = fmaxf(cmax, sv);
            }
        }
        cmax = fmaxf(cmax, __shfl_xor(cmax, 16, 64));
        cmax = fmaxf(cmax, __shfl_xor(cmax, 32, 64));
        const float mn  = fmaxf(m_r, cmax);
        const float scl = __expf(m_r - mn);
        m_r = mn;
        float lsum = 0.f;
#pragma unroll
        for (int f = 0; f < 2; ++f) {
            if (f >= nf) break;
#pragma unroll
            for (int r = 0; r < 4; ++r) {
                const float pv = (p[f][r] <= -1e29f) ? 0.f : __expf(p[f][r] - mn);
                p[f][r] = pv;
                lsum += pv;
            }
        }
        lsum += __shfl_xor(lsum, 16, 64);
        lsum += __shfl_xor(lsum, 32, 64);
        l_r = l_r * scl + lsum;

        float scl4[4];
#pragma unroll
        for (int r = 0; r < 4; ++r) scl4[r] = __shfl(scl, grp * 4 + r, 64);
#pragma unroll
        for (int ds = 0; ds < 4; ++ds)
#pragma unroll
            for (int r = 0; r < 4; ++r) acc[ds][r] *= scl4[r];

#pragma unroll
        for (int f = 0; f < 2; ++f)
#pragma unroll
            for (int r = 0; r < 4; ++r) {
                const int k = 16 * f + grp * 4 + r;
                const int slot = (k >> 3) ^ ((row_l >> 1) & 3);
                const float pv = (f < nf) ? p[f][r] : 0.f;
                Pw[row_l * 32 + slot * 8 + (k & 7)] = f2bf(pv);
            }
        const bf16x8 pa = *reinterpret_cast<const bf16x8*>(
            &Pw[row_l * 32 + ((grp ^ ((row_l >> 1) & 3)) * 8)]);

        int k0 = kcL + grp * 8;
        if (half) k0 = min(k0, 248);
#pragma unroll
        for (int ds = 0; ds < 4; ++ds) {
            const int d = ds * 16 + row_l;
            const bf16x8 vf = *reinterpret_cast<const bf16x8*>(
                &Vt[d * 256 + (((k0 >> 3) ^ (d & 7)) * 8)]);
            acc[ds] = __builtin_amdgcn_mfma_f32_16x16x32_bf16(pa, vf, acc[ds], 0, 0, 0);
        }
    };

    if (!edge) {
        do_chunk(0, true,  false, false, false);
        do_chunk(1, false, false, false, false);
        do_chunk(2, false, false, false, false);
        do_chunk(3, false, false, false, false);
        do_chunk(4, false, true,  true,  false);
    } else {
        const int kw = kstart + wv * 16;
        if (kw       > -32 && kw       < L_SEQ) do_chunk(0, true,  false, false, true);
        if (kw + 32  > -32 && kw + 32  < L_SEQ) do_chunk(1, false, false, false, true);
        if (kw + 64  > -32 && kw + 64  < L_SEQ) do_chunk(2, false, false, false, true);
        if (kw + 96  > -32 && kw + 96  < L_SEQ) do_chunk(3, false, false, false, true);
        if (kw + 128 > -32 && kw + 128 < L_SEQ) do_chunk(4, false, true,  true,  true);
    }

    const float inv = 1.f / l_r;
    float inv4[4];
#pragma unroll
    for (int r = 0; r < 4; ++r) inv4[r] = __shfl(inv, grp * 4 + r, 64);
    const int qg = q0b + wv * 16 + grp * 4;
#pragma unroll
    for (int r = 0; r < 4; ++r)
#pragma unroll
        for (int ds = 0; ds < 4; ++ds)
            att[(size_t)(b * L_SEQ + qg + r) * 512 + h * 64 + ds * 16 + row_l] =
                f2bf(acc[ds][r] * inv4[r]);
}

extern "C" void kernel_launch(void* const* d_in, const int* in_sizes, int n_in,
                              void* d_out, int out_size, void* d_ws, size_t ws_size,
                              hipStream_t stream) {
    const float* x     = (const float*)d_in[0];
    const float* w_in  = (const float*)d_in[1];
    const float* b_in  = (const float*)d_in[2];
    const float* w_out = (const float*)d_in[3];
    const float* b_out = (const float*)d_in[4];
    float* out = (float*)d_out;

    const int B = 8, L = L_SEQ;
    const int M = B * L;  // 16384

    u16* qkv   = (u16*)d_ws;                      // [M, 1536]  bf16
    u16* att   = qkv   + (size_t)M * 1536;        // [M, 512]   bf16
    u16* x_bf  = att   + (size_t)M * 512;         // [M, 512]   bf16
    u16* wi_bf = x_bf  + (size_t)M * 512;         // [1536, 512] bf16
    u16* wo_bf = wi_bf + (size_t)1536 * 512;      // [512, 512] bf16

    {
        const int nx = M * 512 / 8;
        cvt_f32_bf16<<<(nx + 255) / 256, 256, 0, stream>>>(x, x_bf, nx);
        const int nwi = 1536 * 512 / 8;
        cvt_f32_bf16<<<(nwi + 255) / 256, 256, 0, stream>>>(w_in, wi_bf, nwi);
        const int nwo = 512 * 512 / 8;
        cvt_f32_bf16<<<(nwo + 255) / 256, 256, 0, stream>>>(w_out, wo_bf, nwo);
    }

    gemm_bt_bias<true><<<dim3(1536 / 128, M / 128), dim3(256), 0, stream>>>(
        x_bf, wi_bf, b_in, qkv, M, 1536, 512);

    local_attn<<<dim3(NQT, 8, B), dim3(512), 0, stream>>>(qkv, att);

    gemm_bt_bias<false><<<dim3(512 / 128, M / 128), dim3(256), 0, stream>>>(
        att, wo_bf, b_out, out, M, 512, 512);
}